// Round 1
// baseline (756.820 us; speedup 1.0000x reference)
//
#include <hip/hip_runtime.h>
#include <hip/hip_bf16.h>
#include <stdint.h>

#define VOCAB 50000
#define EMB   300
#define EMBP  320   // K padded to multiple of 32
#define HID   128
#define NGATE 512   // 4*HID
#define BATCH 1024
#define SEQ   200

typedef __attribute__((ext_vector_type(8))) short short8;
typedef __attribute__((ext_vector_type(4))) float f32x4;

#define AS1 __attribute__((address_space(1)))
#define AS3 __attribute__((address_space(3)))

static __device__ __forceinline__ void gload_lds16(const void* g, void* s) {
  __builtin_amdgcn_global_load_lds((const AS1 uint32_t*)g, (AS3 uint32_t*)s, 16, 0, 0);
}

static __device__ __forceinline__ unsigned short f2bf(float f) {
  union { float f; unsigned u; } v; v.f = f;
  unsigned r = v.u + 0x7fffu + ((v.u >> 16) & 1u);
  return (unsigned short)(r >> 16);
}
static __device__ __forceinline__ float bf2f(unsigned short b) {
  union { unsigned u; float f; } v; v.u = ((unsigned)b) << 16;
  return v.f;
}
static __device__ __forceinline__ float sigmf(float x) {
  return __fdividef(1.0f, 1.0f + __expf(-x));
}
static __device__ __forceinline__ float tanhf_fast(float x) {
  return __fdividef(2.0f, 1.0f + __expf(-2.0f * x)) - 1.0f;
}

// ---------------- prep: f32 -> bf16 (optionally K-padded with zeros) -------
__global__ void k_cvt_pad(const float* __restrict__ src, unsigned short* __restrict__ dst,
                          int rows, int sc, int dc) {
  int idx = blockIdx.x * blockDim.x + threadIdx.x;
  int cpr = dc >> 3;
  if (idx >= rows * cpr) return;
  int row = idx / cpr, k0 = (idx - row * cpr) * 8;
  uint4 pack;
  unsigned short* v = (unsigned short*)&pack;
#pragma unroll
  for (int j = 0; j < 8; j++) {
    int k = k0 + j;
    v[j] = (k < sc) ? f2bf(src[(long)row * sc + k]) : (unsigned short)0;
  }
  *(uint4*)(dst + (long)row * dc + k0) = pack;
}

__global__ void k_bias(const float* __restrict__ a, const float* __restrict__ b,
                       float* __restrict__ o) {
  int i = blockIdx.x * blockDim.x + threadIdx.x;
  if (i < NGATE) o[i] = a[i] + b[i];
}

// ---------------- kernel 1: gathered GEMM  xg = emb[x] @ w_ih^T  (bf16) ----
// grid: (M/128)*(N/128) = 1600*4 ; block 256 (4 waves, 2x2 of 64x64)
__global__ __launch_bounds__(256) void k_xg_gemm(
    const int* __restrict__ x, const unsigned short* __restrict__ embb,
    const unsigned short* __restrict__ wihb, unsigned short* __restrict__ xg) {
  __shared__ __align__(16) unsigned short Al[128 * 32];
  __shared__ __align__(16) unsigned short Bl[128 * 32];
  const int tid = threadIdx.x;
  const int lane = tid & 63;
  const int tile_n = blockIdx.x & 3, tile_m = blockIdx.x >> 2;
  const int t_idx = tile_m >> 3;            // 1024%128==0 -> whole tile same t
  const int b0 = (tile_m & 7) * 128;
  const int n0 = tile_n * 128;

  // staging chunks: c1 = tid, c2 = tid+256 ; row = c>>2, kchunk = c&3
  const int ar1 = tid >> 2, akc = tid & 3;
  const int ar2 = ar1 + 64;
  const long ridx1 = x[(b0 + ar1) * SEQ + t_idx];
  const long ridx2 = x[(b0 + ar2) * SEQ + t_idx];
  const unsigned short* abase1 = embb + ridx1 * EMBP + akc * 8;
  const unsigned short* abase2 = embb + ridx2 * EMBP + akc * 8;
  const unsigned short* bbase1 = wihb + (long)(n0 + ar1) * EMBP + akc * 8;
  const unsigned short* bbase2 = wihb + (long)(n0 + ar2) * EMBP + akc * 8;
  char* adst1 = (char*)Al + tid * 16;
  char* adst2 = (char*)Al + tid * 16 + 4096;
  char* bdst1 = (char*)Bl + tid * 16;
  char* bdst2 = (char*)Bl + tid * 16 + 4096;

  const int wid = tid >> 6;
  const int wrow = wid >> 1, wcol = wid & 1;
  const unsigned short* Ar = Al + (wrow * 64) * 32;
  const unsigned short* Br = Bl + (wcol * 64) * 32;
  const int l15 = lane & 15, lk = (lane >> 4) * 8;

  f32x4 acc[4][4];
#pragma unroll
  for (int mt = 0; mt < 4; mt++)
#pragma unroll
    for (int nt = 0; nt < 4; nt++) acc[mt][nt] = (f32x4){0.f, 0.f, 0.f, 0.f};

  for (int ks = 0; ks < EMBP / 32; ks++) {
    gload_lds16(abase1 + ks * 32, adst1);
    gload_lds16(abase2 + ks * 32, adst2);
    gload_lds16(bbase1 + ks * 32, bdst1);
    gload_lds16(bbase2 + ks * 32, bdst2);
    __syncthreads();
    short8 af[4], bf[4];
#pragma unroll
    for (int mt = 0; mt < 4; mt++)
      af[mt] = *(const short8*)(Ar + (mt * 16 + l15) * 32 + lk);
#pragma unroll
    for (int nt = 0; nt < 4; nt++)
      bf[nt] = *(const short8*)(Br + (nt * 16 + l15) * 32 + lk);
#pragma unroll
    for (int mt = 0; mt < 4; mt++)
#pragma unroll
      for (int nt = 0; nt < 4; nt++)
        acc[mt][nt] = __builtin_amdgcn_mfma_f32_16x16x32_bf16(af[mt], bf[nt], acc[mt][nt], 0, 0, 0);
    __syncthreads();
  }

  const int m_base = tile_m * 128 + wrow * 64;
  const int colg = n0 + wcol * 64 + l15;
  const int rsub = (lane >> 4) * 4;
#pragma unroll
  for (int mt = 0; mt < 4; mt++)
#pragma unroll
    for (int nt = 0; nt < 4; nt++)
#pragma unroll
      for (int j = 0; j < 4; j++) {
        const long m = m_base + mt * 16 + rsub + j;
        xg[m * NGATE + colg + nt * 16] = f2bf(acc[mt][nt][j]);
      }
}

// ---------------- kernel 2: sequential LSTM, batch-partitioned -------------
// grid 64 blocks x 256 threads; block owns 16 batch rows, wave w owns gate w.
__global__ __launch_bounds__(256, 1) void k_lstm(
    const unsigned short* __restrict__ xg, const unsigned short* __restrict__ whhb,
    const float* __restrict__ bias, float* __restrict__ hfin) {
  __shared__ __align__(16) unsigned short h_lds[16 * 128];   // bf16, XOR-swizzled
  __shared__ __align__(16) float gate_lds[16 * 512];         // f32 raw accums, swizzled
  const int tid = threadIdx.x;
  const int lane = tid & 63;
  const int wid = tid >> 6;
  const int b0 = blockIdx.x * 16;

  // B (w_hh) fragments, held in registers for all 200 steps.
  // B[k][n] = w_hh[n][k]; lane holds n = wid*128+nt*16+(lane&15), k = kt*32+(lane>>4)*8+j
  short8 bfr[8][4];
#pragma unroll
  for (int nt = 0; nt < 8; nt++) {
    const int col = wid * 128 + nt * 16 + (lane & 15);
#pragma unroll
    for (int kt = 0; kt < 4; kt++)
      bfr[nt][kt] = *(const short8*)(whhb + col * HID + kt * 32 + (lane >> 4) * 8);
  }

  // update-phase identity: thread owns (row urow, hidden j0..j0+7)
  const int urow = tid & 15;
  const int j0 = (tid >> 4) * 8;
  const int uswz = (urow & 7) << 4;

  float bias_r[4][8];
#pragma unroll
  for (int g = 0; g < 4; g++)
#pragma unroll
    for (int j = 0; j < 8; j++) bias_r[g][j] = bias[g * 128 + j0 + j];

  float c_r[8], h_r[8];
#pragma unroll
  for (int j = 0; j < 8; j++) { c_r[j] = 0.0f; h_r[j] = 0.0f; }

  ((uint4*)h_lds)[tid] = make_uint4(0, 0, 0, 0);
  __syncthreads();

  const int arow = lane & 15;
  const int akb = (lane >> 4) * 16;
  const int aswz = (arow & 7) << 4;
  const char* hbase = (const char*)h_lds;

  for (int t = 0; t < SEQ; t++) {
    // xg for the update phase — issue early, used after the barrier
    uint4 xgv[4];
    const long xbase = ((long)t * BATCH + b0 + urow) * NGATE;
#pragma unroll
    for (int g = 0; g < 4; g++)
      xgv[g] = *(const uint4*)(xg + xbase + g * 128 + j0);

    // A = h tile [16 x 128] from swizzled LDS
    short8 af[4];
#pragma unroll
    for (int kt = 0; kt < 4; kt++)
      af[kt] = *(const short8*)(hbase + arow * 256 + ((kt * 64 + akb) ^ aswz));

    f32x4 acc[8];
#pragma unroll
    for (int nt = 0; nt < 8; nt++) acc[nt] = (f32x4){0.f, 0.f, 0.f, 0.f};
#pragma unroll
    for (int kt = 0; kt < 4; kt++)
#pragma unroll
      for (int nt = 0; nt < 8; nt++)
        acc[nt] = __builtin_amdgcn_mfma_f32_16x16x32_bf16(af[kt], bfr[nt][kt], acc[nt], 0, 0, 0);

    // scatter raw gate accums to swizzled f32 LDS
#pragma unroll
    for (int nt = 0; nt < 8; nt++) {
      const int bytein = (wid * 128 + nt * 16 + (lane & 15)) * 4;
#pragma unroll
      for (int j = 0; j < 4; j++) {
        const int row = (lane >> 4) * 4 + j;
        const int addr = row * 2048 + (((bytein & ~15) ^ ((row & 7) << 4)) | (bytein & 15));
        *(float*)((char*)gate_lds + addr) = acc[nt][j];
      }
    }
    __syncthreads();

    // gather i,f,g,o for my (row, j0..j0+7), add xg + bias, activate
    float pre[4][8];
#pragma unroll
    for (int g = 0; g < 4; g++) {
      const int bytein = (g * 128 + j0) * 4;
      const f32x4 lo = *(const f32x4*)((const char*)gate_lds + urow * 2048 + (bytein ^ uswz));
      const f32x4 hi = *(const f32x4*)((const char*)gate_lds + urow * 2048 + ((bytein + 16) ^ uswz));
      const unsigned short* xp = (const unsigned short*)&xgv[g];
#pragma unroll
      for (int j = 0; j < 4; j++) {
        pre[g][j] = lo[j] + bf2f(xp[j]) + bias_r[g][j];
        pre[g][j + 4] = hi[j] + bf2f(xp[j + 4]) + bias_r[g][j + 4];
      }
    }

    uint4 hp;
    unsigned short* hb = (unsigned short*)&hp;
#pragma unroll
    for (int j = 0; j < 8; j++) {
      const float iv = sigmf(pre[0][j]);
      const float fv = sigmf(pre[1][j]);
      const float gv = tanhf_fast(pre[2][j]);
      const float ov = sigmf(pre[3][j]);
      const float c = fv * c_r[j] + iv * gv;
      c_r[j] = c;
      const float h = ov * tanhf_fast(c);
      h_r[j] = h;
      hb[j] = f2bf(h);
    }
    *(uint4*)((char*)h_lds + urow * 256 + ((j0 * 2) ^ uswz)) = hp;
    __syncthreads();
  }

#pragma unroll
  for (int j = 0; j < 8; j++)
    hfin[(b0 + urow) * HID + j0 + j] = h_r[j];
}

// ---------------- kernel 3: FC head, one wave per batch row ----------------
__global__ void k_head(const float* __restrict__ hfin,
                       const float* __restrict__ fc1w, const float* __restrict__ fc1b,
                       const float* __restrict__ fc2w, const float* __restrict__ fc2b,
                       float* __restrict__ out) {
  const int tid = threadIdx.x;
  const int lane = tid & 63;
  const int wid = tid >> 6;
  const int row = blockIdx.x * 4 + wid;
  const float* h = hfin + row * HID;
  const float* w = fc1w + lane * HID;
  float acc = 0.0f;
#pragma unroll
  for (int k = 0; k < HID; k += 4) {
    const f32x4 hv = *(const f32x4*)(h + k);
    const f32x4 wv = *(const f32x4*)(w + k);
    acc += hv[0] * wv[0] + hv[1] * wv[1] + hv[2] * wv[2] + hv[3] * wv[3];
  }
  const float h1 = fmaxf(acc + fc1b[lane], 0.0f);
  float v = h1 * fc2w[lane];
#pragma unroll
  for (int off = 32; off > 0; off >>= 1) v += __shfl_down(v, off, 64);
  if (lane == 0) out[row] = sigmf(v + fc2b[0]);
}

// ---------------------------------------------------------------------------
extern "C" void kernel_launch(void* const* d_in, const int* in_sizes, int n_in,
                              void* d_out, int out_size, void* d_ws, size_t ws_size,
                              hipStream_t stream) {
  const int*   x    = (const int*)d_in[0];
  const float* emb  = (const float*)d_in[1];
  const float* w_ih = (const float*)d_in[2];
  const float* w_hh = (const float*)d_in[3];
  const float* b_ih = (const float*)d_in[4];
  const float* b_hh = (const float*)d_in[5];
  const float* fc1w = (const float*)d_in[6];
  const float* fc1b = (const float*)d_in[7];
  const float* fc2w = (const float*)d_in[8];
  const float* fc2b = (const float*)d_in[9];
  float* out = (float*)d_out;
  char* ws = (char*)d_ws;

  // workspace layout (243 MB total, all offsets 256B aligned)
  unsigned short* embb = (unsigned short*)(ws + 0);            // 50000*320*2 = 32,000,000
  unsigned short* wihb = (unsigned short*)(ws + 32000000);     // 512*320*2   =    327,680
  unsigned short* whhb = (unsigned short*)(ws + 32327680);     // 512*128*2   =    131,072
  float*          biasp= (float*)(ws + 32458752);              // 512*4       =      2,048
  float*          hfinp= (float*)(ws + 32460800);              // 1024*128*4  =    524,288
  unsigned short* xgb  = (unsigned short*)(ws + 32985088);     // 204800*512*2= 209,715,200

  k_cvt_pad<<<dim3((VOCAB * (EMBP / 8) + 255) / 256), dim3(256), 0, stream>>>(emb, embb, VOCAB, EMB, EMBP);
  k_cvt_pad<<<dim3((NGATE * (EMBP / 8) + 255) / 256), dim3(256), 0, stream>>>(w_ih, wihb, NGATE, EMB, EMBP);
  k_cvt_pad<<<dim3((NGATE * (HID / 8) + 255) / 256), dim3(256), 0, stream>>>(w_hh, whhb, NGATE, HID, HID);
  k_bias<<<dim3(2), dim3(256), 0, stream>>>(b_ih, b_hh, biasp);
  k_xg_gemm<<<dim3(1600 * 4), dim3(256), 0, stream>>>(x, embb, wihb, xgb);
  k_lstm<<<dim3(64), dim3(256), 0, stream>>>(xgb, whhb, biasp, hfinp);
  k_head<<<dim3(256), dim3(256), 0, stream>>>(hfinp, fc1w, fc1b, fc2w, fc2b, out);
  (void)in_sizes; (void)n_in; (void)out_size; (void)ws_size;
}

// Round 2
// 514.953 us; speedup vs baseline: 1.4697x; 1.4697x over previous
//
#include <hip/hip_runtime.h>
#include <hip/hip_bf16.h>
#include <stdint.h>

#define VOCAB 50000
#define EMB   300
#define EMBP  320   // K padded to multiple of 32
#define HID   128
#define NGATE 512   // 4*HID
#define BATCH 1024
#define SEQ   200

typedef __attribute__((ext_vector_type(8))) short short8;
typedef __attribute__((ext_vector_type(4))) float f32x4;

#define AS1 __attribute__((address_space(1)))
#define AS3 __attribute__((address_space(3)))

static __device__ __forceinline__ void gload_lds16(const void* g, void* s) {
  __builtin_amdgcn_global_load_lds((const AS1 uint32_t*)g, (AS3 uint32_t*)s, 16, 0, 0);
}

static __device__ __forceinline__ unsigned short f2bf(float f) {
  union { float f; unsigned u; } v; v.f = f;
  unsigned r = v.u + 0x7fffu + ((v.u >> 16) & 1u);
  return (unsigned short)(r >> 16);
}
static __device__ __forceinline__ float bf2f(unsigned short b) {
  union { unsigned u; float f; } v; v.u = ((unsigned)b) << 16;
  return v.f;
}
static __device__ __forceinline__ float sigmf(float x) {
  return __fdividef(1.0f, 1.0f + __expf(-x));
}
static __device__ __forceinline__ float tanhf_fast(float x) {
  return __fdividef(2.0f, 1.0f + __expf(-2.0f * x)) - 1.0f;
}

// ---------------- prep: f32 -> bf16 (K-padded; optional gate-interleave) ---
// perm=1: dst row n' = (n&127)*4 + (n>>7)  (i.e. [gate][hid] -> [hid][gate])
__global__ void k_cvt_pad(const float* __restrict__ src, unsigned short* __restrict__ dst,
                          int rows, int sc, int dc, int perm) {
  int idx = blockIdx.x * blockDim.x + threadIdx.x;
  int cpr = dc >> 3;
  if (idx >= rows * cpr) return;
  int row = idx / cpr, k0 = (idx - row * cpr) * 8;
  uint4 pack;
  unsigned short* v = (unsigned short*)&pack;
#pragma unroll
  for (int j = 0; j < 8; j++) {
    int k = k0 + j;
    v[j] = (k < sc) ? f2bf(src[(long)row * sc + k]) : (unsigned short)0;
  }
  int drow = perm ? ((row & 127) * 4 + (row >> 7)) : row;
  *(uint4*)(dst + (long)drow * dc + k0) = pack;
}

__global__ void k_bias(const float* __restrict__ a, const float* __restrict__ b,
                       float* __restrict__ o) {
  int i = blockIdx.x * blockDim.x + threadIdx.x;
  if (i < NGATE) o[i] = a[i] + b[i];
}

// ---------------- kernel 1: gathered GEMM  xg = emb[x] @ w_ih_perm^T ------
// grid: (M/128)*(N/128) = 1600*4 ; block 256 (4 waves, 2x2 of 64x64)
// N dimension is the PERMUTED gate axis: n' = hid*4 + gate
__global__ __launch_bounds__(256) void k_xg_gemm(
    const int* __restrict__ x, const unsigned short* __restrict__ embb,
    const unsigned short* __restrict__ wihb, unsigned short* __restrict__ xg) {
  __shared__ __align__(16) unsigned short Al[128 * 32];
  __shared__ __align__(16) unsigned short Bl[128 * 32];
  const int tid = threadIdx.x;
  const int lane = tid & 63;
  const int tile_n = blockIdx.x & 3, tile_m = blockIdx.x >> 2;
  const int t_idx = tile_m >> 3;            // 1024%128==0 -> whole tile same t
  const int b0 = (tile_m & 7) * 128;
  const int n0 = tile_n * 128;

  // staging chunks: c1 = tid, c2 = tid+256 ; row = c>>2, kchunk = c&3
  const int ar1 = tid >> 2, akc = tid & 3;
  const int ar2 = ar1 + 64;
  const long ridx1 = x[(b0 + ar1) * SEQ + t_idx];
  const long ridx2 = x[(b0 + ar2) * SEQ + t_idx];
  const unsigned short* abase1 = embb + ridx1 * EMBP + akc * 8;
  const unsigned short* abase2 = embb + ridx2 * EMBP + akc * 8;
  const unsigned short* bbase1 = wihb + (long)(n0 + ar1) * EMBP + akc * 8;
  const unsigned short* bbase2 = wihb + (long)(n0 + ar2) * EMBP + akc * 8;
  char* adst1 = (char*)Al + tid * 16;
  char* adst2 = (char*)Al + tid * 16 + 4096;
  char* bdst1 = (char*)Bl + tid * 16;
  char* bdst2 = (char*)Bl + tid * 16 + 4096;

  const int wid = tid >> 6;
  const int wrow = wid >> 1, wcol = wid & 1;
  const unsigned short* Ar = Al + (wrow * 64) * 32;
  const unsigned short* Br = Bl + (wcol * 64) * 32;
  const int l15 = lane & 15, lk = (lane >> 4) * 8;

  f32x4 acc[4][4];
#pragma unroll
  for (int mt = 0; mt < 4; mt++)
#pragma unroll
    for (int nt = 0; nt < 4; nt++) acc[mt][nt] = (f32x4){0.f, 0.f, 0.f, 0.f};

  for (int ks = 0; ks < EMBP / 32; ks++) {
    gload_lds16(abase1 + ks * 32, adst1);
    gload_lds16(abase2 + ks * 32, adst2);
    gload_lds16(bbase1 + ks * 32, bdst1);
    gload_lds16(bbase2 + ks * 32, bdst2);
    __syncthreads();
    short8 af[4], bf[4];
#pragma unroll
    for (int mt = 0; mt < 4; mt++)
      af[mt] = *(const short8*)(Ar + (mt * 16 + l15) * 32 + lk);
#pragma unroll
    for (int nt = 0; nt < 4; nt++)
      bf[nt] = *(const short8*)(Br + (nt * 16 + l15) * 32 + lk);
#pragma unroll
    for (int mt = 0; mt < 4; mt++)
#pragma unroll
      for (int nt = 0; nt < 4; nt++)
        acc[mt][nt] = __builtin_amdgcn_mfma_f32_16x16x32_bf16(af[mt], bf[nt], acc[mt][nt], 0, 0, 0);
    __syncthreads();
  }

  const int m_base = tile_m * 128 + wrow * 64;
  const int colg = n0 + wcol * 64 + l15;
  const int rsub = (lane >> 4) * 4;
#pragma unroll
  for (int mt = 0; mt < 4; mt++)
#pragma unroll
    for (int nt = 0; nt < 4; nt++)
#pragma unroll
      for (int j = 0; j < 4; j++) {
        const long m = m_base + mt * 16 + rsub + j;
        xg[m * NGATE + colg + nt * 16] = f2bf(acc[mt][nt][j]);
      }
}

// ---------------- kernel 2: sequential LSTM, gate-exchange-free ------------
// grid 64 blocks x 512 threads (8 waves). Block owns 16 batch rows.
// Wave w owns hidden block w*16..w*16+15 and computes ALL FOUR gates for it
// (n-tiles at cols g*128 + w*16), so i,f,g,o for a given (row,hid) land in
// the SAME thread's accumulators -> cell update is pure-register, c persists
// in registers for all 200 steps. Only h crosses waves (via swizzled LDS,
// double-buffered, ONE barrier per step).
__global__ __launch_bounds__(512, 2) void k_lstm(
    const unsigned short* __restrict__ xg, const unsigned short* __restrict__ whhb,
    const float* __restrict__ bias, float* __restrict__ hfin) {
  __shared__ __align__(16) unsigned short h_lds[2 * 16 * 128];  // 8KB, XOR-swizzled
  const int tid = threadIdx.x;
  const int lane = tid & 63;
  const int wid = tid >> 6;        // 0..7 -> hidden block
  const int b0 = blockIdx.x * 16;
  const int l15 = lane & 15;
  const int lgrp = lane >> 4;      // 0..3
  const int hid = wid * 16 + l15;  // 0..127, this thread's hidden column

  // B (w_hh) fragments in registers for all steps: gate g, k-tile kt
  // B[col][k], col = g*128 + hid, k = kt*32 + lgrp*8
  short8 bfr[4][4];
#pragma unroll
  for (int g = 0; g < 4; g++)
#pragma unroll
    for (int kt = 0; kt < 4; kt++)
      bfr[g][kt] = *(const short8*)(whhb + (g * 128 + hid) * HID + kt * 32 + lgrp * 8);

  float bias_r[4];
#pragma unroll
  for (int g = 0; g < 4; g++) bias_r[g] = bias[g * 128 + hid];

  float c_r[4], h_r[4];
#pragma unroll
  for (int j = 0; j < 4; j++) { c_r[j] = 0.0f; h_r[j] = 0.0f; }

  // zero both h buffers (512 threads x 16B = 8KB)
  ((uint4*)h_lds)[tid] = make_uint4(0, 0, 0, 0);
  __syncthreads();

  // xg layout: elem index ((t*BATCH + row)*HID + hid)*4 + gate ; 4 gates = 8B
  uint2 xcur[4];
#pragma unroll
  for (int j = 0; j < 4; j++)
    xcur[j] = *(const uint2*)(xg + ((long)(b0 + lgrp * 4 + j) * HID + hid) * 4);

  const char* hb = (const char*)h_lds;

  for (int t = 0; t < SEQ; t++) {
    // prefetch xg for t+1 (consumed NEXT iteration -> full-step latency hiding)
    const int tn = (t + 1 < SEQ) ? t + 1 : t;
    uint2 xnxt[4];
#pragma unroll
    for (int j = 0; j < 4; j++)
      xnxt[j] = *(const uint2*)(xg + ((long)(tn * BATCH + b0 + lgrp * 4 + j) * HID + hid) * 4);

    // A = h tile [16 x 128] from swizzled LDS buffer (t&1)
    const char* cb = hb + (t & 1) * 4096;
    short8 af[4];
#pragma unroll
    for (int kt = 0; kt < 4; kt++)
      af[kt] = *(const short8*)(cb + l15 * 256 + ((kt * 64 + lgrp * 16) ^ ((l15 & 7) << 4)));

    f32x4 acc[4];
#pragma unroll
    for (int g = 0; g < 4; g++) acc[g] = (f32x4){0.f, 0.f, 0.f, 0.f};
#pragma unroll
    for (int kt = 0; kt < 4; kt++)
#pragma unroll
      for (int g = 0; g < 4; g++)
        acc[g] = __builtin_amdgcn_mfma_f32_16x16x32_bf16(af[kt], bfr[g][kt], acc[g], 0, 0, 0);

    // cell update: all 4 gates for (row, hid) are in this thread's registers
    char* nb = (char*)h_lds + ((t + 1) & 1) * 4096;
#pragma unroll
    for (int j = 0; j < 4; j++) {
      const unsigned short* xp = (const unsigned short*)&xcur[j];
      const float pi = acc[0][j] + bf2f(xp[0]) + bias_r[0];
      const float pf = acc[1][j] + bf2f(xp[1]) + bias_r[1];
      const float pg = acc[2][j] + bf2f(xp[2]) + bias_r[2];
      const float po = acc[3][j] + bf2f(xp[3]) + bias_r[3];
      const float iv = sigmf(pi);
      const float fv = sigmf(pf);
      const float gv = tanhf_fast(pg);
      const float ov = sigmf(po);
      const float c = fv * c_r[j] + iv * gv;
      c_r[j] = c;
      const float h = ov * tanhf_fast(c);
      h_r[j] = h;
      const int r = lgrp * 4 + j;
      *(unsigned short*)(nb + r * 256 + ((hid * 2) ^ ((r & 7) << 4))) = f2bf(h);
    }
    __syncthreads();
#pragma unroll
    for (int j = 0; j < 4; j++) xcur[j] = xnxt[j];
  }

#pragma unroll
  for (int j = 0; j < 4; j++)
    hfin[(b0 + lgrp * 4 + j) * HID + hid] = h_r[j];
}

// ---------------- kernel 3: FC head, one wave per batch row ----------------
__global__ void k_head(const float* __restrict__ hfin,
                       const float* __restrict__ fc1w, const float* __restrict__ fc1b,
                       const float* __restrict__ fc2w, const float* __restrict__ fc2b,
                       float* __restrict__ out) {
  const int tid = threadIdx.x;
  const int lane = tid & 63;
  const int wid = tid >> 6;
  const int row = blockIdx.x * 4 + wid;
  const float* h = hfin + row * HID;
  const float* w = fc1w + lane * HID;
  float acc = 0.0f;
#pragma unroll
  for (int k = 0; k < HID; k += 4) {
    const f32x4 hv = *(const f32x4*)(h + k);
    const f32x4 wv = *(const f32x4*)(w + k);
    acc += hv[0] * wv[0] + hv[1] * wv[1] + hv[2] * wv[2] + hv[3] * wv[3];
  }
  const float h1 = fmaxf(acc + fc1b[lane], 0.0f);
  float v = h1 * fc2w[lane];
#pragma unroll
  for (int off = 32; off > 0; off >>= 1) v += __shfl_down(v, off, 64);
  if (lane == 0) out[row] = sigmf(v + fc2b[0]);
}

// ---------------------------------------------------------------------------
extern "C" void kernel_launch(void* const* d_in, const int* in_sizes, int n_in,
                              void* d_out, int out_size, void* d_ws, size_t ws_size,
                              hipStream_t stream) {
  const int*   x    = (const int*)d_in[0];
  const float* emb  = (const float*)d_in[1];
  const float* w_ih = (const float*)d_in[2];
  const float* w_hh = (const float*)d_in[3];
  const float* b_ih = (const float*)d_in[4];
  const float* b_hh = (const float*)d_in[5];
  const float* fc1w = (const float*)d_in[6];
  const float* fc1b = (const float*)d_in[7];
  const float* fc2w = (const float*)d_in[8];
  const float* fc2b = (const float*)d_in[9];
  float* out = (float*)d_out;
  char* ws = (char*)d_ws;

  // workspace layout (243 MB total, all offsets 256B aligned)
  unsigned short* embb = (unsigned short*)(ws + 0);            // 50000*320*2 = 32,000,000
  unsigned short* wihb = (unsigned short*)(ws + 32000000);     // 512*320*2   =    327,680
  unsigned short* whhb = (unsigned short*)(ws + 32327680);     // 512*128*2   =    131,072
  float*          biasp= (float*)(ws + 32458752);              // 512*4       =      2,048
  float*          hfinp= (float*)(ws + 32460800);              // 1024*128*4  =    524,288
  unsigned short* xgb  = (unsigned short*)(ws + 32985088);     // 204800*512*2= 209,715,200

  k_cvt_pad<<<dim3((VOCAB * (EMBP / 8) + 255) / 256), dim3(256), 0, stream>>>(emb, embb, VOCAB, EMB, EMBP, 0);
  k_cvt_pad<<<dim3((NGATE * (EMBP / 8) + 255) / 256), dim3(256), 0, stream>>>(w_ih, wihb, NGATE, EMB, EMBP, 1);
  k_cvt_pad<<<dim3((NGATE * (HID / 8) + 255) / 256), dim3(256), 0, stream>>>(w_hh, whhb, NGATE, HID, HID, 0);
  k_bias<<<dim3(2), dim3(256), 0, stream>>>(b_ih, b_hh, biasp);
  k_xg_gemm<<<dim3(1600 * 4), dim3(256), 0, stream>>>(x, embb, wihb, xgb);
  k_lstm<<<dim3(64), dim3(512), 0, stream>>>(xgb, whhb, biasp, hfinp);
  k_head<<<dim3(256), dim3(256), 0, stream>>>(hfinp, fc1w, fc1b, fc2w, fc2b, out);
  (void)in_sizes; (void)n_in; (void)out_size; (void)ws_size;
}

// Round 3
// 350.665 us; speedup vs baseline: 2.1582x; 1.4685x over previous
//
#include <hip/hip_runtime.h>
#include <hip/hip_bf16.h>
#include <stdint.h>

#define VOCAB 50000
#define EMB   300
#define EMBP  320   // K padded to multiple of 32
#define HID   128
#define NGATE 512   // 4*HID
#define BATCH 1024
#define SEQ   200
#define L2E   1.4426950408889634f

typedef __attribute__((ext_vector_type(8))) short short8;
typedef __attribute__((ext_vector_type(4))) float f32x4;

#define AS1 __attribute__((address_space(1)))
#define AS3 __attribute__((address_space(3)))

static __device__ __forceinline__ void gload_lds16(const void* g, void* s) {
  __builtin_amdgcn_global_load_lds((const AS1 uint32_t*)g, (AS3 uint32_t*)s, 16, 0, 0);
}

static __device__ __forceinline__ unsigned short f2bf(float f) {
  union { float f; unsigned u; } v; v.f = f;
  unsigned r = v.u + 0x7fffu + ((v.u >> 16) & 1u);
  return (unsigned short)(r >> 16);
}
static __device__ __forceinline__ float blo2f(unsigned u) {
  union { unsigned u; float f; } v; v.u = u << 16; return v.f;
}
static __device__ __forceinline__ float bhi2f(unsigned u) {
  union { unsigned u; float f; } v; v.u = u & 0xffff0000u; return v.f;
}
static __device__ __forceinline__ float sigmf(float x) {
  return __fdividef(1.0f, 1.0f + __expf(-x));
}
// z pre-scaled by log2(e): sigmoid(a) = 1/(1+2^-z)
static __device__ __forceinline__ float sig2(float z) {
  return __builtin_amdgcn_rcpf(1.0f + __builtin_amdgcn_exp2f(-z));
}

// ---------------- prep: f32 -> bf16 (K-pad; optional perm / gate scale) ----
__global__ void k_cvt_pad(const float* __restrict__ src, unsigned short* __restrict__ dst,
                          int rows, int sc, int dc, int perm, int smode) {
  int idx = blockIdx.x * blockDim.x + threadIdx.x;
  int cpr = dc >> 3;
  if (idx >= rows * cpr) return;
  int row = idx / cpr, k0 = (idx - row * cpr) * 8;
  float s = 1.0f;
  if (smode) s = ((row >> 7) == 2) ? (2.0f * L2E) : L2E;
  uint4 pack;
  unsigned short* v = (unsigned short*)&pack;
#pragma unroll
  for (int j = 0; j < 8; j++) {
    int k = k0 + j;
    v[j] = (k < sc) ? f2bf(src[(long)row * sc + k] * s) : (unsigned short)0;
  }
  int drow = perm ? ((row & 127) * 4 + (row >> 7)) : row;
  *(uint4*)(dst + (long)drow * dc + k0) = pack;
}

// permuted+scaled bias: o[hid*4+g] = (a[g*128+hid]+b[...]) * s_g
__global__ void k_bias(const float* __restrict__ a, const float* __restrict__ b,
                       float* __restrict__ o) {
  int i = blockIdx.x * blockDim.x + threadIdx.x;
  if (i < NGATE) {
    int g = i >> 7, hid = i & 127;
    float s = (g == 2) ? (2.0f * L2E) : L2E;
    o[hid * 4 + g] = (a[i] + b[i]) * s;
  }
}

// ---------------- kernel 1: gathered GEMM  xg = emb[x] @ w_ih_perm^T + bias
__global__ __launch_bounds__(256) void k_xg_gemm(
    const int* __restrict__ x, const unsigned short* __restrict__ embb,
    const unsigned short* __restrict__ wihb, const float* __restrict__ biasp,
    unsigned short* __restrict__ xg) {
  __shared__ __align__(16) unsigned short Al[128 * 32];
  __shared__ __align__(16) unsigned short Bl[128 * 32];
  const int tid = threadIdx.x;
  const int lane = tid & 63;
  const int tile_n = blockIdx.x & 3, tile_m = blockIdx.x >> 2;
  const int t_idx = tile_m >> 3;
  const int b0 = (tile_m & 7) * 128;
  const int n0 = tile_n * 128;

  const int ar1 = tid >> 2, akc = tid & 3;
  const int ar2 = ar1 + 64;
  const long ridx1 = x[(b0 + ar1) * SEQ + t_idx];
  const long ridx2 = x[(b0 + ar2) * SEQ + t_idx];
  const unsigned short* abase1 = embb + ridx1 * EMBP + akc * 8;
  const unsigned short* abase2 = embb + ridx2 * EMBP + akc * 8;
  const unsigned short* bbase1 = wihb + (long)(n0 + ar1) * EMBP + akc * 8;
  const unsigned short* bbase2 = wihb + (long)(n0 + ar2) * EMBP + akc * 8;
  char* adst1 = (char*)Al + tid * 16;
  char* adst2 = (char*)Al + tid * 16 + 4096;
  char* bdst1 = (char*)Bl + tid * 16;
  char* bdst2 = (char*)Bl + tid * 16 + 4096;

  const int wid = tid >> 6;
  const int wrow = wid >> 1, wcol = wid & 1;
  const unsigned short* Ar = Al + (wrow * 64) * 32;
  const unsigned short* Br = Bl + (wcol * 64) * 32;
  const int l15 = lane & 15, lk = (lane >> 4) * 8;

  f32x4 acc[4][4];
#pragma unroll
  for (int mt = 0; mt < 4; mt++)
#pragma unroll
    for (int nt = 0; nt < 4; nt++) acc[mt][nt] = (f32x4){0.f, 0.f, 0.f, 0.f};

  for (int ks = 0; ks < EMBP / 32; ks++) {
    gload_lds16(abase1 + ks * 32, adst1);
    gload_lds16(abase2 + ks * 32, adst2);
    gload_lds16(bbase1 + ks * 32, bdst1);
    gload_lds16(bbase2 + ks * 32, bdst2);
    __syncthreads();
    short8 af[4], bf[4];
#pragma unroll
    for (int mt = 0; mt < 4; mt++)
      af[mt] = *(const short8*)(Ar + (mt * 16 + l15) * 32 + lk);
#pragma unroll
    for (int nt = 0; nt < 4; nt++)
      bf[nt] = *(const short8*)(Br + (nt * 16 + l15) * 32 + lk);
#pragma unroll
    for (int mt = 0; mt < 4; mt++)
#pragma unroll
      for (int nt = 0; nt < 4; nt++)
        acc[mt][nt] = __builtin_amdgcn_mfma_f32_16x16x32_bf16(af[mt], bf[nt], acc[mt][nt], 0, 0, 0);
    __syncthreads();
  }

  const int m_base = tile_m * 128 + wrow * 64;
  const int colg = n0 + wcol * 64 + l15;
  const int rsub = (lane >> 4) * 4;
  float bv[4];
#pragma unroll
  for (int nt = 0; nt < 4; nt++) bv[nt] = biasp[colg + nt * 16];
#pragma unroll
  for (int mt = 0; mt < 4; mt++)
#pragma unroll
    for (int nt = 0; nt < 4; nt++)
#pragma unroll
      for (int j = 0; j < 4; j++) {
        const long m = m_base + mt * 16 + rsub + j;
        xg[m * NGATE + colg + nt * 16] = f2bf(acc[mt][nt][j] + bv[nt]);
      }
}

// ---------------- kernel 2: sequential LSTM, raw-barrier pipeline ----------
__global__ __launch_bounds__(512, 2) void k_lstm(
    const unsigned short* __restrict__ xg, const unsigned short* __restrict__ whhb,
    float* __restrict__ hfin) {
  __shared__ __align__(16) unsigned short h_lds[2 * 16 * 128];
  const int tid = threadIdx.x;
  const int lane = tid & 63;
  const int wid = tid >> 6;
  const int b0 = blockIdx.x * 16;
  const int l15 = lane & 15;
  const int lgrp = lane >> 4;
  const int hid = wid * 16 + l15;

  short8 bfr[4][4];
#pragma unroll
  for (int g = 0; g < 4; g++)
#pragma unroll
    for (int kt = 0; kt < 4; kt++)
      bfr[g][kt] = *(const short8*)(whhb + (g * 128 + hid) * HID + kt * 32 + lgrp * 8);

  float c_r[4], h_r[4];
#pragma unroll
  for (int j = 0; j < 4; j++) { c_r[j] = 0.0f; h_r[j] = 0.0f; }

  ((uint4*)h_lds)[tid] = make_uint4(0, 0, 0, 0);
  __syncthreads();

  int rdoff[4], wroff[4];
#pragma unroll
  for (int kt = 0; kt < 4; kt++)
    rdoff[kt] = l15 * 256 + ((kt * 64 + lgrp * 16) ^ ((l15 & 7) << 4));
#pragma unroll
  for (int j = 0; j < 4; j++) {
    const int r = lgrp * 4 + j;
    wroff[j] = r * 256 + ((hid * 2) ^ ((r & 7) << 4));
  }
  const char* lb = (const char*)h_lds;

  const unsigned short* xbase = xg + ((long)(b0 + lgrp * 4) * HID + hid) * 4;
  const long TSTEP = (long)BATCH * HID * 4;
  uint2 xA[4], xB[4];
#pragma unroll
  for (int j = 0; j < 4; j++) xA[j] = *(const uint2*)(xbase + j * (HID * 4));
#pragma unroll
  for (int j = 0; j < 4; j++) xB[j] = *(const uint2*)(xbase + TSTEP + j * (HID * 4));
  const unsigned short* xnext = xbase + 2 * TSTEP;

#define STEP_BODY(XS, RB, WB, T)                                               \
  {                                                                            \
    float xf[16];                                                              \
    _Pragma("unroll") for (int j = 0; j < 4; j++) {                            \
      xf[j * 4 + 0] = blo2f(XS[j].x);                                          \
      xf[j * 4 + 1] = bhi2f(XS[j].x);                                          \
      xf[j * 4 + 2] = blo2f(XS[j].y);                                          \
      xf[j * 4 + 3] = bhi2f(XS[j].y);                                          \
    }                                                                          \
    if ((T) + 2 < SEQ) {                                                       \
      _Pragma("unroll") for (int j = 0; j < 4; j++)                            \
        XS[j] = *(const uint2*)(xnext + j * (HID * 4));                        \
    }                                                                          \
    short8 af[4];                                                              \
    _Pragma("unroll") for (int kt = 0; kt < 4; kt++)                           \
      af[kt] = *(const short8*)(lb + (RB) + rdoff[kt]);                        \
    f32x4 acc[4];                                                              \
    _Pragma("unroll") for (int g = 0; g < 4; g++)                              \
      acc[g] = (f32x4){0.f, 0.f, 0.f, 0.f};                                    \
    _Pragma("unroll") for (int kt = 0; kt < 4; kt++)                           \
      _Pragma("unroll") for (int g = 0; g < 4; g++)                            \
        acc[g] = __builtin_amdgcn_mfma_f32_16x16x32_bf16(af[kt], bfr[g][kt],   \
                                                         acc[g], 0, 0, 0);     \
    _Pragma("unroll") for (int j = 0; j < 4; j++) {                            \
      const float zi = acc[0][j] + xf[j * 4 + 0];                              \
      const float zf = acc[1][j] + xf[j * 4 + 1];                              \
      const float zg = acc[2][j] + xf[j * 4 + 2];                              \
      const float zo = acc[3][j] + xf[j * 4 + 3];                              \
      const float iv = sig2(zi);                                               \
      const float fv = sig2(zf);                                               \
      const float gv = 2.0f * sig2(zg) - 1.0f;                                 \
      const float ov = sig2(zo);                                               \
      const float c = fv * c_r[j] + iv * gv;                                   \
      c_r[j] = c;                                                              \
      const float tc = 2.0f * sig2(c * (2.0f * L2E)) - 1.0f;                   \
      const float h = ov * tc;                                                 \
      h_r[j] = h;                                                              \
      *(unsigned short*)((char*)h_lds + (WB) + wroff[j]) = f2bf(h);            \
    }                                                                          \
    asm volatile("s_waitcnt lgkmcnt(0)" ::: "memory");                         \
    __builtin_amdgcn_s_barrier();                                              \
    __builtin_amdgcn_sched_barrier(0);                                         \
  }

  for (int t = 0; t < SEQ; t += 2) {
    STEP_BODY(xA, 0, 4096, t);
    xnext += TSTEP;
    STEP_BODY(xB, 4096, 0, t + 1);
    xnext += TSTEP;
  }
#undef STEP_BODY

#pragma unroll
  for (int j = 0; j < 4; j++)
    hfin[(b0 + lgrp * 4 + j) * HID + hid] = h_r[j];
}

// ---------------- kernel 3: FC head, one wave per batch row ----------------
__global__ void k_head(const float* __restrict__ hfin,
                       const float* __restrict__ fc1w, const float* __restrict__ fc1b,
                       const float* __restrict__ fc2w, const float* __restrict__ fc2b,
                       float* __restrict__ out) {
  const int tid = threadIdx.x;
  const int lane = tid & 63;
  const int wid = tid >> 6;
  const int row = blockIdx.x * 4 + wid;
  const float* h = hfin + row * HID;
  const float* w = fc1w + lane * HID;
  float acc = 0.0f;
#pragma unroll
  for (int k = 0; k < HID; k += 4) {
    const f32x4 hv = *(const f32x4*)(h + k);
    const f32x4 wv = *(const f32x4*)(w + k);
    acc += hv[0] * wv[0] + hv[1] * wv[1] + hv[2] * wv[2] + hv[3] * wv[3];
  }
  const float h1 = fmaxf(acc + fc1b[lane], 0.0f);
  float v = h1 * fc2w[lane];
#pragma unroll
  for (int off = 32; off > 0; off >>= 1) v += __shfl_down(v, off, 64);
  if (lane == 0) out[row] = sigmf(v + fc2b[0]);
}

// ---------------------------------------------------------------------------
extern "C" void kernel_launch(void* const* d_in, const int* in_sizes, int n_in,
                              void* d_out, int out_size, void* d_ws, size_t ws_size,
                              hipStream_t stream) {
  const int*   x    = (const int*)d_in[0];
  const float* emb  = (const float*)d_in[1];
  const float* w_ih = (const float*)d_in[2];
  const float* w_hh = (const float*)d_in[3];
  const float* b_ih = (const float*)d_in[4];
  const float* b_hh = (const float*)d_in[5];
  const float* fc1w = (const float*)d_in[6];
  const float* fc1b = (const float*)d_in[7];
  const float* fc2w = (const float*)d_in[8];
  const float* fc2b = (const float*)d_in[9];
  float* out = (float*)d_out;
  char* ws = (char*)d_ws;

  unsigned short* embb = (unsigned short*)(ws + 0);
  unsigned short* wihb = (unsigned short*)(ws + 32000000);
  unsigned short* whhb = (unsigned short*)(ws + 32327680);
  float*          biasp= (float*)(ws + 32458752);
  float*          hfinp= (float*)(ws + 32460800);
  unsigned short* xgb  = (unsigned short*)(ws + 32985088);

  k_cvt_pad<<<dim3((VOCAB * (EMBP / 8) + 255) / 256), dim3(256), 0, stream>>>(emb, embb, VOCAB, EMB, EMBP, 0, 0);
  k_cvt_pad<<<dim3((NGATE * (EMBP / 8) + 255) / 256), dim3(256), 0, stream>>>(w_ih, wihb, NGATE, EMB, EMBP, 1, 1);
  k_cvt_pad<<<dim3((NGATE * (HID / 8) + 255) / 256), dim3(256), 0, stream>>>(w_hh, whhb, NGATE, HID, HID, 0, 1);
  k_bias<<<dim3(2), dim3(256), 0, stream>>>(b_ih, b_hh, biasp);
  k_xg_gemm<<<dim3(1600 * 4), dim3(256), 0, stream>>>(x, embb, wihb, biasp, xgb);
  k_lstm<<<dim3(64), dim3(512), 0, stream>>>(xgb, whhb, hfinp);
  k_head<<<dim3(256), dim3(256), 0, stream>>>(hfinp, fc1w, fc1b, fc2w, fc2b, out);
  (void)in_sizes; (void)n_in; (void)out_size; (void)ws_size;
}